// Round 6
// baseline (327.843 us; speedup 1.0000x reference)
//
#include <hip/hip_runtime.h>
#include <math.h>

#define N_SETS 4096
#define SETS_PER_BLOCK 8
#define GRID_MAIN (N_SETS / SETS_PER_BLOCK)   // 512 blocks, all co-resident (2/CU)

typedef _Float16 f16;
typedef __attribute__((ext_vector_type(8))) _Float16 f16x8;
typedef __attribute__((ext_vector_type(4))) _Float16 f16x4;
typedef __attribute__((ext_vector_type(4))) float     f32x4;

// ---------------- ws layout ----------------
#define WS_PE    0         // fp32 [64][256]  65536
#define WS_QH    65536     // f16  [64][32]   4096
#define WS_WKV   69632     // f16  [64][256]  32768  (rows 0-31 Wk, 32-63 Wv)
#define WS_WMAPH 102400    // f16  [256][32]  16384
#define WS_PEH   118784    // f16  [64][256]  32768
#define WS_PTR   151552    // int  [4097]

// aux1: blocks [0,768) -> batch_ptr + out2 echo; blocks [768,832) -> pe table
__global__ void k_aux1(const int* __restrict__ batch, float* __restrict__ out2,
                       int* __restrict__ ptr, int N, float* __restrict__ pe) {
    int blk = blockIdx.x;
    if (blk < 768) {
        int i = blk * 256 + threadIdx.x;
        if (i >= N) return;
        int b = batch[i];
        out2[i] = (float)b;
        if (i == 0 || batch[i - 1] != b) ptr[b] = i;
        if (i == N - 1) ptr[N_SETS] = N;
    } else {
        int idx = (blk - 768) * 256 + threadIdx.x;   // 0..16383
        int p = idx >> 8, i = idx & 255;
        float e   = (float)(2 * (i / 2)) / 256.0f;
        float inv = powf(10000.0f, -e);
        float ang = (float)p * inv;
        pe[idx] = (i & 1) ? cosf(ang) : sinf(ang);
    }
}

// aux2: [0,96) weight f16 convert; [96,160) peh convert; [160,168) qh
__global__ void k_aux2(const float* __restrict__ Wk, const float* __restrict__ Wv,
                       const float* __restrict__ Wq, const float* __restrict__ Wmap,
                       const float* __restrict__ pe, f16* __restrict__ wkv,
                       f16* __restrict__ wmaph, f16* __restrict__ peh,
                       f16* __restrict__ qh) {
    int blk = blockIdx.x;
    if (blk < 96) {
        int idx = blk * 256 + threadIdx.x;           // 0..24575
        if (idx < 16384) {
            int j = idx >> 8, d = idx & 255;
            float v = (j < 32) ? Wk[j * 256 + d] : Wv[(j - 32) * 256 + d];
            wkv[idx] = (f16)v;
        } else {
            int i2 = idx - 16384;
            wmaph[i2] = (f16)Wmap[i2];
        }
    } else if (blk < 160) {
        int idx = (blk - 96) * 256 + threadIdx.x;    // 0..16383
        peh[idx] = (f16)pe[idx];
    } else {
        int idx = (blk - 160) * 256 + threadIdx.x;   // 0..2047
        int pos = idx >> 5, k = idx & 31;
        const float* pr = pe + pos * 256;
        const float* wr = Wq + k * 256;
        float s = 0.f;
        for (int d = 0; d < 256; d += 4) {
            float4 a = *(const float4*)(pr + d);
            float4 b = *(const float4*)(wr + d);
            s += a.x * b.x + a.y * b.y + a.z * b.z + a.w * b.w;
        }
        qh[idx] = (f16)s;
    }
}

// 512 threads = two independent 4-wave set-groups sharing one weight staging.
// Group g handles sets blockIdx.x*8 + 4g + j, j=0..3 (j,j+4 have equal n -> balanced).
// LDS map (77824 B, 2 blocks/CU = 16 waves/CU):
//   [0,     32768)  wsh f16 [64][256] swz ((j&7)<<4)  (Wk rows 0-31, Wv 32-63)
//   [32768, 49152)  wmh f16 [256][32] swz ((d&7)<<4)
//   per group g at 49152 + g*14336:
//     +0     yshT f16 [64c][64r] swz ((c&7)<<4)   8192 B
//     +8192  zT   f16 [32c][32r] swz ((c&3)<<4)   2048 B
//     +10240 dsh  f16 [64m][32v] swz ((m&7)<<4)   4096 B
// Barriers: 2 per set. GEMM3->GEMM4 (dsh) is same-wave-same-rows; next set's
// GEMM1 ysh overwrite is fenced by the previous GEMM2 barrier pair.
__global__ __launch_bounds__(512, 4) void k_main(
        const float* __restrict__ x,     const f16* __restrict__ wkv,
        const f16* __restrict__ wmaph,   const f16* __restrict__ qh,
        const f16* __restrict__ peh,     const float* __restrict__ bmap,
        const int* __restrict__ ptr,     float* __restrict__ out) {
    __shared__ char lds[77824];

    const int t    = threadIdx.x;
    const int wid  = t >> 6;
    const int grp  = wid >> 2;            // 0,1
    const int wv   = wid & 3;             // wave within group
    const int l15  = t & 15;
    const int lhi  = (t & 63) >> 4;       // 0..3
    const int arow = 16 * wv + l15;
    const int swz7 = (l15 & 7) << 4;
    char* ysh = lds + 49152 + grp * 14336;
    char* zsh = ysh + 8192;
    char* dsh = ysh + 10240;

    int pv[SETS_PER_BLOCK + 1];
    #pragma unroll
    for (int i = 0; i <= SETS_PER_BLOCK; ++i)
        pv[i] = ptr[blockIdx.x * SETS_PER_BLOCK + i];

    // ---- stage wsh (Wk|Wv) ----
    #pragma unroll
    for (int i = 0; i < 4; ++i) {
        int c = t + 512 * i;
        int j = c >> 5, d0 = (c & 31) * 8;
        *(f16x8*)(lds + ((j * 512 + d0 * 2) ^ ((j & 7) << 4))) =
            *(const f16x8*)(wkv + j * 256 + d0);
    }
    // ---- stage wmh ----
    #pragma unroll
    for (int i = 0; i < 2; ++i) {
        int c = t + 512 * i;
        int d = c >> 2, v0 = (c & 3) * 8;
        *(f16x8*)(lds + 32768 + ((d * 64 + v0 * 2) ^ ((d & 7) << 4))) =
            *(const f16x8*)(wmaph + d * 32 + v0);
    }
    // ---- per-lane set-invariant registers ----
    f16x8 pef[8];
    #pragma unroll
    for (int ks = 0; ks < 8; ++ks)
        pef[ks] = *(const f16x8*)(peh + arow * 256 + ks * 32 + lhi * 8);
    const f16x8 qreg = *(const f16x8*)(qh + arow * 32 + lhi * 8);
    float bm[16];
    #pragma unroll
    for (int nt = 0; nt < 16; ++nt) bm[nt] = bmap[16 * nt + l15];

    // ---- prefetch x rows of this group's first set ----
    const int base = 4 * grp;
    float4 xf[16];
    {
        const int s0 = pv[base], n0 = pv[base + 1] - pv[base];
        if (arow < n0) {
            const float* xr = x + (size_t)(s0 + arow) * 256 + lhi * 8;
            #pragma unroll
            for (int ks = 0; ks < 8; ++ks) {
                xf[2 * ks]     = *(const float4*)(xr + ks * 32);
                xf[2 * ks + 1] = *(const float4*)(xr + ks * 32 + 4);
            }
        }
    }
    __syncthreads();

    for (int j = 0; j < 4; ++j) {
        const int s = pv[base + j], n = pv[base + j + 1] - s;
        const int n32 = (n + 31) & ~31;

        // convert current x + PE -> areg (f16)
        f16x8 areg[8];
        if (arow < n) {
            #pragma unroll
            for (int ks = 0; ks < 8; ++ks) {
                float4 a = xf[2 * ks], a2 = xf[2 * ks + 1];
                f16x8 h;
                h[0]=(f16)a.x;  h[1]=(f16)a.y;  h[2]=(f16)a.z;  h[3]=(f16)a.w;
                h[4]=(f16)a2.x; h[5]=(f16)a2.y; h[6]=(f16)a2.z; h[7]=(f16)a2.w;
                areg[ks] = h + pef[ks];
            }
        } else {
            #pragma unroll
            for (int ks = 0; ks < 8; ++ks) {
                f16x8 h;
                #pragma unroll
                for (int ii = 0; ii < 8; ++ii) h[ii] = (f16)0.f;
                areg[ks] = h;
            }
        }
        // prefetch next set's x (overlaps GEMM1..4)
        if (j + 1 < 4) {
            const int s1 = pv[base + j + 1], n1 = pv[base + j + 2] - pv[base + j + 1];
            if (arow < n1) {
                const float* xr = x + (size_t)(s1 + arow) * 256 + lhi * 8;
                #pragma unroll
                for (int ks = 0; ks < 8; ++ks) {
                    xf[2 * ks]     = *(const float4*)(xr + ks * 32);
                    xf[2 * ks + 1] = *(const float4*)(xr + ks * 32 + 4);
                }
            }
        }

        // ---- GEMM1: Y = (X+PE)*Wkv^T -> yshT (transposed) ----
        if (16 * wv < n32) {
            f32x4 acc[4];
            #pragma unroll
            for (int nt = 0; nt < 4; ++nt) acc[nt] = (f32x4){0.f, 0.f, 0.f, 0.f};
            #pragma unroll
            for (int ks = 0; ks < 8; ++ks) {
                #pragma unroll
                for (int nt = 0; nt < 4; ++nt) {
                    f16x8 bf = *(const f16x8*)(lds +
                        (((16 * nt + l15) * 512 + ks * 64 + lhi * 16) ^ swz7));
                    acc[nt] = __builtin_amdgcn_mfma_f32_16x16x32_f16(areg[ks], bf, acc[nt], 0, 0, 0);
                }
            }
            const int row0 = 16 * wv + lhi * 4;
            #pragma unroll
            for (int nt = 0; nt < 4; ++nt) {
                const int col = 16 * nt + l15;
                f16x4 h4;
                #pragma unroll
                for (int q = 0; q < 4; ++q) h4[q] = (f16)acc[nt][q];
                *(f16x4*)(ysh + ((col * 128 + row0 * 2) ^ swz7)) = h4;
            }
        }
        __syncthreads();

        // ---- GEMM2: Z = YV^T * YK -> zT ----
        {
            const int it = wv >> 1, jt = wv & 1;
            f32x4 zacc = {0.f, 0.f, 0.f, 0.f};
            const int ca = 32 + 16 * it + l15, cb = 16 * jt + l15;
            const int nks = n32 >> 5;
            for (int ks = 0; ks < nks; ++ks) {
                const int r2 = ks * 64 + lhi * 16;
                f16x8 av = *(const f16x8*)(ysh + ((ca * 128 + r2) ^ swz7));
                f16x8 bk = *(const f16x8*)(ysh + ((cb * 128 + r2) ^ swz7));
                zacc = __builtin_amdgcn_mfma_f32_16x16x32_f16(av, bk, zacc, 0, 0, 0);
            }
            const int zc = 16 * jt + l15, zr0 = 16 * it + lhi * 4;
            f16x4 h4;
            #pragma unroll
            for (int q = 0; q < 4; ++q) h4[q] = (f16)zacc[q];
            *(f16x4*)(zsh + ((zc * 64 + zr0 * 2) ^ ((l15 & 3) << 4))) = h4;
        }
        __syncthreads();

        // ---- GEMM3: dec = query * Z -> dsh (same-wave rows; no barrier to GEMM4) ----
        if (16 * wv < n) {
            const int k2 = lhi * 16;
            f16x8 bz0 = *(const f16x8*)(zsh + ((l15 * 64 + k2) ^ ((l15 & 3) << 4)));
            f16x8 bz1 = *(const f16x8*)(zsh + (((16 + l15) * 64 + k2) ^ ((l15 & 3) << 4)));
            f32x4 dd0 = {0.f, 0.f, 0.f, 0.f}, dd1 = {0.f, 0.f, 0.f, 0.f};
            dd0 = __builtin_amdgcn_mfma_f32_16x16x32_f16(qreg, bz0, dd0, 0, 0, 0);
            dd1 = __builtin_amdgcn_mfma_f32_16x16x32_f16(qreg, bz1, dd1, 0, 0, 0);
            #pragma unroll
            for (int q = 0; q < 4; ++q) {
                const int m = 16 * wv + lhi * 4 + q;
                *(f16*)(dsh + ((m * 64 + l15 * 2) ^ ((m & 7) << 4)))        = (f16)dd0[q];
                *(f16*)(dsh + ((m * 64 + (16 + l15) * 2) ^ ((m & 7) << 4))) = (f16)dd1[q];
            }
        }

        // ---- GEMM4: out = dec * Wmap^T + bmap ----
        if (16 * wv < n) {
            const int k2 = lhi * 16;
            f16x8 ad = *(const f16x8*)(dsh + (((16 * wv + l15) * 64 + k2) ^ swz7));
            const int row0 = 16 * wv + lhi * 4;
            float* ob = out + (size_t)s * 256;
            #pragma unroll
            for (int nt = 0; nt < 16; ++nt) {
                const int dcol = 16 * nt + l15;
                f16x8 bw = *(const f16x8*)(lds + 32768 + ((dcol * 64 + k2) ^ swz7));
                f32x4 o = {0.f, 0.f, 0.f, 0.f};
                o = __builtin_amdgcn_mfma_f32_16x16x32_f16(ad, bw, o, 0, 0, 0);
                #pragma unroll
                for (int q = 0; q < 4; ++q) {
                    const int row = row0 + q;
                    if (row < n) ob[(size_t)row * 256 + dcol] = o[q] + bm[nt];
                }
            }
        }
    }
}

extern "C" void kernel_launch(void* const* d_in, const int* in_sizes, int n_in,
                              void* d_out, int out_size, void* d_ws, size_t ws_size,
                              hipStream_t stream) {
    const float* x    = (const float*)d_in[0];
    const int*   batch= (const int*)  d_in[1];
    const float* Wk   = (const float*)d_in[2];
    const float* Wv   = (const float*)d_in[3];
    const float* Wq   = (const float*)d_in[4];
    const float* Wmap = (const float*)d_in[5];
    const float* bmap = (const float*)d_in[6];
    float* out = (float*)d_out;

    const int N = in_sizes[1];                 // 196608 rows
    float* pe    = (float*)((char*)d_ws + WS_PE);
    f16*   qh    = (f16*)  ((char*)d_ws + WS_QH);
    f16*   wkv   = (f16*)  ((char*)d_ws + WS_WKV);
    f16*   wmaph = (f16*)  ((char*)d_ws + WS_WMAPH);
    f16*   peh   = (f16*)  ((char*)d_ws + WS_PEH);
    int*   ptr   = (int*)  ((char*)d_ws + WS_PTR);
    float* out2  = out + (size_t)N * 256;      // output 1: batch echo as floats

    k_aux1<<<832, 256, 0, stream>>>(batch, out2, ptr, N, pe);
    k_aux2<<<168, 256, 0, stream>>>(Wk, Wv, Wq, Wmap, pe, wkv, wmaph, peh, qh);
    k_main<<<GRID_MAIN, 512, 0, stream>>>(x, wkv, wmaph, qh, peh, bmap, ptr, out);
}

// Round 7
// 115.449 us; speedup vs baseline: 2.8397x; 2.8397x over previous
//
#include <hip/hip_runtime.h>
#include <math.h>

#define N_SETS 4096
#define SETS_PER_BLOCK 4
#define GRID_MAIN (N_SETS / SETS_PER_BLOCK)   // 1024 blocks; 3/CU resident (LDS-bound)

typedef _Float16 f16;
typedef __attribute__((ext_vector_type(8))) _Float16 f16x8;
typedef __attribute__((ext_vector_type(4))) _Float16 f16x4;
typedef __attribute__((ext_vector_type(4))) float     f32x4;

// ---------------- ws layout ----------------
#define WS_PE    0         // fp32 [64][256]  65536
#define WS_QH    65536     // f16  [64][32]   4096
#define WS_WKV   69632     // f16  [64][256]  32768  (rows 0-31 Wk, 32-63 Wv)
#define WS_WMAPH 102400    // f16  [256][32]  16384
#define WS_PEH   118784    // f16  [64][256]  32768
#define WS_PTR   151552    // int  [4097]

// aux1: blocks [0,768) -> batch_ptr + out2 echo; blocks [768,832) -> pe table
__global__ void k_aux1(const int* __restrict__ batch, float* __restrict__ out2,
                       int* __restrict__ ptr, int N, float* __restrict__ pe) {
    int blk = blockIdx.x;
    if (blk < 768) {
        int i = blk * 256 + threadIdx.x;
        if (i >= N) return;
        int b = batch[i];
        out2[i] = (float)b;
        if (i == 0 || batch[i - 1] != b) ptr[b] = i;
        if (i == N - 1) ptr[N_SETS] = N;
    } else {
        int idx = (blk - 768) * 256 + threadIdx.x;   // 0..16383
        int p = idx >> 8, i = idx & 255;
        float e   = (float)(2 * (i / 2)) / 256.0f;
        float inv = powf(10000.0f, -e);
        float ang = (float)p * inv;
        pe[idx] = (i & 1) ? cosf(ang) : sinf(ang);
    }
}

// aux2: [0,96) weight f16 convert; [96,160) peh convert; [160,168) qh
__global__ void k_aux2(const float* __restrict__ Wk, const float* __restrict__ Wv,
                       const float* __restrict__ Wq, const float* __restrict__ Wmap,
                       const float* __restrict__ pe, f16* __restrict__ wkv,
                       f16* __restrict__ wmaph, f16* __restrict__ peh,
                       f16* __restrict__ qh) {
    int blk = blockIdx.x;
    if (blk < 96) {
        int idx = blk * 256 + threadIdx.x;           // 0..24575
        if (idx < 16384) {
            int j = idx >> 8, d = idx & 255;
            float v = (j < 32) ? Wk[j * 256 + d] : Wv[(j - 32) * 256 + d];
            wkv[idx] = (f16)v;
        } else {
            int i2 = idx - 16384;
            wmaph[i2] = (f16)Wmap[i2];
        }
    } else if (blk < 160) {
        int idx = (blk - 96) * 256 + threadIdx.x;    // 0..16383
        peh[idx] = (f16)pe[idx];
    } else {
        int idx = (blk - 160) * 256 + threadIdx.x;   // 0..2047
        int pos = idx >> 5, k = idx & 31;
        const float* pr = pe + pos * 256;
        const float* wr = Wq + k * 256;
        float s = 0.f;
        for (int d = 0; d < 256; d += 4) {
            float4 a = *(const float4*)(pr + d);
            float4 b = *(const float4*)(wr + d);
            s += a.x * b.x + a.y * b.y + a.z * b.z + a.w * b.w;
        }
        qh[idx] = (f16)s;
    }
}

// Fused encoder+decoder, 4 sets/block, 4 waves/block (256 thr).
// LDS map (43008 B -> 3 blocks/CU = 12 waves/CU; VGPR must stay <=128):
//   [0,     32768)  wsh f16 [64][256] swz ((j&7)<<4)  (Wk rows 0-31, Wv 32-63)
//   [32768, 40960)  yshT f16 [64c][64r] swz ((c&7)<<4) | dsh f16 [64m][32v] swz ((m&7)<<4) overlay
//   [40960, 43008)  zT  f16 [32c][32r] swz ((c&3)<<4)
// GEMM4 is column-split: wave wv owns col-tiles nt=4wv..4wv+3; Wmap B-frags
// live in 16 set-invariant VGPRs (no wmh LDS region). dsh is cross-wave ->
// barrier after GEMM3. 4 barriers/set.
__global__ __launch_bounds__(256, 2) void k_main(
        const float* __restrict__ x,     const f16* __restrict__ wkv,
        const f16* __restrict__ wmaph,   const f16* __restrict__ qh,
        const f16* __restrict__ peh,     const float* __restrict__ bmap,
        const int* __restrict__ ptr,     float* __restrict__ out) {
    __shared__ char lds[43008];
    char* ysh = lds + 32768;
    char* dsh = lds + 32768;   // overlay (ysh dead after GEMM2's barrier)
    char* zsh = lds + 40960;

    const int t    = threadIdx.x;
    const int wv   = t >> 6;
    const int l15  = t & 15;
    const int lhi  = (t & 63) >> 4;       // 0..3
    const int arow = 16 * wv + l15;
    const int swz7 = (l15 & 7) << 4;

    int pv[SETS_PER_BLOCK + 1];
    #pragma unroll
    for (int i = 0; i <= SETS_PER_BLOCK; ++i)
        pv[i] = ptr[blockIdx.x * SETS_PER_BLOCK + i];

    // ---- stage wsh (Wk|Wv) ----
    #pragma unroll
    for (int i2 = 0; i2 < 8; ++i2) {
        int c = t + 256 * i2;
        int j = c >> 5, d0 = (c & 31) * 8;
        *(f16x8*)(lds + ((j * 512 + d0 * 2) ^ ((j & 7) << 4))) =
            *(const f16x8*)(wkv + j * 256 + d0);
    }
    // ---- per-lane set-invariant registers ----
    f16x8 pef[8];
    #pragma unroll
    for (int ks = 0; ks < 8; ++ks)
        pef[ks] = *(const f16x8*)(peh + arow * 256 + ks * 32 + lhi * 8);
    const f16x8 qreg = *(const f16x8*)(qh + arow * 32 + lhi * 8);
    f16x8 bwreg[4];
    float bm[4];
    #pragma unroll
    for (int i = 0; i < 4; ++i) {
        const int dcol = 64 * wv + 16 * i + l15;
        bwreg[i] = *(const f16x8*)(wmaph + dcol * 32 + lhi * 8);
        bm[i] = bmap[dcol];
    }

    // ---- prefetch first half (ks 0..3) of set 0's x rows ----
    float4 xf[8];
    {
        const int s0 = pv[0], n0 = pv[1] - pv[0];
        if (arow < n0) {
            const float* xr = x + (size_t)(s0 + arow) * 256 + lhi * 8;
            #pragma unroll
            for (int ks = 0; ks < 4; ++ks) {
                xf[2 * ks]     = *(const float4*)(xr + ks * 32);
                xf[2 * ks + 1] = *(const float4*)(xr + ks * 32 + 4);
            }
        }
    }
    __syncthreads();

    for (int j = 0; j < SETS_PER_BLOCK; ++j) {
        const int s = pv[j], n = pv[j + 1] - s;
        const int n32 = (n + 31) & ~31;
        const float* xr = x + (size_t)(s + arow) * 256 + lhi * 8;

        // build areg: prefetched half + freshly-loaded half, + PE, -> f16
        f16x8 areg[8];
        if (arow < n) {
            #pragma unroll
            for (int ks = 0; ks < 4; ++ks) {
                float4 a = xf[2 * ks], a2 = xf[2 * ks + 1];
                f16x8 h;
                h[0]=(f16)a.x;  h[1]=(f16)a.y;  h[2]=(f16)a.z;  h[3]=(f16)a.w;
                h[4]=(f16)a2.x; h[5]=(f16)a2.y; h[6]=(f16)a2.z; h[7]=(f16)a2.w;
                areg[ks] = h + pef[ks];
            }
            #pragma unroll
            for (int ks = 4; ks < 8; ++ks) {
                float4 a  = *(const float4*)(xr + ks * 32);
                float4 a2 = *(const float4*)(xr + ks * 32 + 4);
                f16x8 h;
                h[0]=(f16)a.x;  h[1]=(f16)a.y;  h[2]=(f16)a.z;  h[3]=(f16)a.w;
                h[4]=(f16)a2.x; h[5]=(f16)a2.y; h[6]=(f16)a2.z; h[7]=(f16)a2.w;
                areg[ks] = h + pef[ks];
            }
        } else {
            #pragma unroll
            for (int ks = 0; ks < 8; ++ks) {
                f16x8 h;
                #pragma unroll
                for (int ii = 0; ii < 8; ++ii) h[ii] = (f16)0.f;
                areg[ks] = h;
            }
        }
        // prefetch next set's first half (overlaps GEMM1..4)
        if (j + 1 < SETS_PER_BLOCK) {
            const int s1 = pv[j + 1], n1 = pv[j + 2] - pv[j + 1];
            if (arow < n1) {
                const float* xr1 = x + (size_t)(s1 + arow) * 256 + lhi * 8;
                #pragma unroll
                for (int ks = 0; ks < 4; ++ks) {
                    xf[2 * ks]     = *(const float4*)(xr1 + ks * 32);
                    xf[2 * ks + 1] = *(const float4*)(xr1 + ks * 32 + 4);
                }
            }
        }

        // ---- GEMM1: Y = (X+PE)*Wkv^T -> yshT (transposed) ----
        if (16 * wv < n32) {
            f32x4 acc[4];
            #pragma unroll
            for (int nt = 0; nt < 4; ++nt) acc[nt] = (f32x4){0.f, 0.f, 0.f, 0.f};
            #pragma unroll
            for (int ks = 0; ks < 8; ++ks) {
                #pragma unroll
                for (int nt = 0; nt < 4; ++nt) {
                    f16x8 bf = *(const f16x8*)(lds +
                        (((16 * nt + l15) * 512 + ks * 64 + lhi * 16) ^ swz7));
                    acc[nt] = __builtin_amdgcn_mfma_f32_16x16x32_f16(areg[ks], bf, acc[nt], 0, 0, 0);
                }
            }
            const int row0 = 16 * wv + lhi * 4;
            #pragma unroll
            for (int nt = 0; nt < 4; ++nt) {
                const int col = 16 * nt + l15;
                f16x4 h4;
                #pragma unroll
                for (int q = 0; q < 4; ++q) h4[q] = (f16)acc[nt][q];
                *(f16x4*)(ysh + ((col * 128 + row0 * 2) ^ swz7)) = h4;
            }
        }
        __syncthreads();

        // ---- GEMM2: Z = YV^T * YK -> zT ----
        {
            const int it = wv >> 1, jt = wv & 1;
            f32x4 zacc = {0.f, 0.f, 0.f, 0.f};
            const int ca = 32 + 16 * it + l15, cb = 16 * jt + l15;
            const int nks = n32 >> 5;
            for (int ks = 0; ks < nks; ++ks) {
                const int r2 = ks * 64 + lhi * 16;
                f16x8 av = *(const f16x8*)(ysh + ((ca * 128 + r2) ^ swz7));
                f16x8 bk = *(const f16x8*)(ysh + ((cb * 128 + r2) ^ swz7));
                zacc = __builtin_amdgcn_mfma_f32_16x16x32_f16(av, bk, zacc, 0, 0, 0);
            }
            const int zc = 16 * jt + l15, zr0 = 16 * it + lhi * 4;
            f16x4 h4;
            #pragma unroll
            for (int q = 0; q < 4; ++q) h4[q] = (f16)zacc[q];
            *(f16x4*)(zsh + ((zc * 64 + zr0 * 2) ^ ((l15 & 3) << 4))) = h4;
        }
        __syncthreads();

        // ---- GEMM3: dec = query * Z -> dsh (overlay ysh; cross-wave read next) ----
        if (16 * wv < n) {
            const int k2 = lhi * 16;
            f16x8 bz0 = *(const f16x8*)(zsh + ((l15 * 64 + k2) ^ ((l15 & 3) << 4)));
            f16x8 bz1 = *(const f16x8*)(zsh + (((16 + l15) * 64 + k2) ^ ((l15 & 3) << 4)));
            f32x4 dd0 = {0.f, 0.f, 0.f, 0.f}, dd1 = {0.f, 0.f, 0.f, 0.f};
            dd0 = __builtin_amdgcn_mfma_f32_16x16x32_f16(qreg, bz0, dd0, 0, 0, 0);
            dd1 = __builtin_amdgcn_mfma_f32_16x16x32_f16(qreg, bz1, dd1, 0, 0, 0);
            #pragma unroll
            for (int q = 0; q < 4; ++q) {
                const int m = 16 * wv + lhi * 4 + q;
                *(f16*)(dsh + ((m * 64 + l15 * 2) ^ ((m & 7) << 4)))        = (f16)dd0[q];
                *(f16*)(dsh + ((m * 64 + (16 + l15) * 2) ^ ((m & 7) << 4))) = (f16)dd1[q];
            }
        }
        __syncthreads();

        // ---- GEMM4 (column-split): out cols [64wv,64wv+64) for all rows ----
        {
            const int k2 = lhi * 16;
            float* ob = out + (size_t)s * 256;
            #pragma unroll
            for (int mt = 0; mt < 4; ++mt) {
                if (16 * mt < n) {
                    f16x8 ad = *(const f16x8*)(dsh + (((16 * mt + l15) * 64 + k2) ^ swz7));
                    const int row0 = 16 * mt + lhi * 4;
                    #pragma unroll
                    for (int i = 0; i < 4; ++i) {
                        const int dcol = 64 * wv + 16 * i + l15;
                        f32x4 o = {0.f, 0.f, 0.f, 0.f};
                        o = __builtin_amdgcn_mfma_f32_16x16x32_f16(ad, bwreg[i], o, 0, 0, 0);
                        #pragma unroll
                        for (int q = 0; q < 4; ++q) {
                            const int row = row0 + q;
                            if (row < n) ob[(size_t)row * 256 + dcol] = o[q] + bm[i];
                        }
                    }
                }
            }
        }
        __syncthreads();
    }
}

extern "C" void kernel_launch(void* const* d_in, const int* in_sizes, int n_in,
                              void* d_out, int out_size, void* d_ws, size_t ws_size,
                              hipStream_t stream) {
    const float* x    = (const float*)d_in[0];
    const int*   batch= (const int*)  d_in[1];
    const float* Wk   = (const float*)d_in[2];
    const float* Wv   = (const float*)d_in[3];
    const float* Wq   = (const float*)d_in[4];
    const float* Wmap = (const float*)d_in[5];
    const float* bmap = (const float*)d_in[6];
    float* out = (float*)d_out;

    const int N = in_sizes[1];                 // 196608 rows
    float* pe    = (float*)((char*)d_ws + WS_PE);
    f16*   qh    = (f16*)  ((char*)d_ws + WS_QH);
    f16*   wkv   = (f16*)  ((char*)d_ws + WS_WKV);
    f16*   wmaph = (f16*)  ((char*)d_ws + WS_WMAPH);
    f16*   peh   = (f16*)  ((char*)d_ws + WS_PEH);
    int*   ptr   = (int*)  ((char*)d_ws + WS_PTR);
    float* out2  = out + (size_t)N * 256;      // output 1: batch echo as floats

    k_aux1<<<832, 256, 0, stream>>>(batch, out2, ptr, N, pe);
    k_aux2<<<168, 256, 0, stream>>>(Wk, Wv, Wq, Wmap, pe, wkv, wmaph, peh, qh);
    k_main<<<GRID_MAIN, 256, 0, stream>>>(x, wkv, wmaph, qh, peh, bmap, ptr, out);
}